// Round 1
// 313.618 us; speedup vs baseline: 1.0017x; 1.0017x over previous
//
#include <hip/hip_runtime.h>

#define IN_F 4096
#define OUT_F 14336
#define NG 32          // quant groups per row (4096/128)
#define NB 8           // batch
#define RPW 7          // rows per wave
#define RPB 28         // rows per block (4 waves * 7)
#define NBLK 512       // 14336 / 28 ; exactly 2 blocks per CU

typedef int v4i __attribute__((ext_vector_type(4)));

// Fused RMSNorm + dequant GEMV.
// Phase 1: every block redundantly computes the 8 per-batch rsqrt factors from
//          x (128 KB, L2/L3-resident broadcast; ~2 us overlapped across 512 blocks).
// Phase 2: stream W nontemporally (224 MiB, the mandatory-traffic floor),
//          normalize x on the fly (x * r[b] * nw[c]), dequant w = q*s+m, FMA.
// Epilogue: LDS transpose (stride 225 -> conflict-free), 224 threads tree-sum.
__global__ __launch_bounds__(256, 2) void fused_gemv_k(
    const float* __restrict__ x, const int* __restrict__ W,
    const float2* __restrict__ smv, const float* __restrict__ nw,
    const float* __restrict__ bias, float* __restrict__ out) {
  const int t = threadIdx.x;
  const int lane = t & 63;
  const int wave = t >> 6;
  const int row0 = blockIdx.x * RPB + wave * RPW;

  __shared__ float red[4][NB];
  __shared__ float p[64][225];

  // ---------------- Phase 1: RMS factors ----------------
  float r_[NB];
  {
    float ss[NB];
#pragma unroll
    for (int b = 0; b < NB; ++b) ss[b] = 0.f;
#pragma unroll
    for (int i = 0; i < 4; ++i) {
      const int idx = i * 256 + t;  // float4 index within a 4096-float row
#pragma unroll
      for (int b = 0; b < NB; ++b) {
        const float4 v = reinterpret_cast<const float4*>(x + b * IN_F)[idx];
        ss[b] += v.x * v.x + v.y * v.y + v.z * v.z + v.w * v.w;
      }
    }
#pragma unroll
    for (int b = 0; b < NB; ++b) {
#pragma unroll
      for (int m = 1; m < 64; m <<= 1) ss[b] += __shfl_xor(ss[b], m, 64);
    }
    if (lane == 0) {
#pragma unroll
      for (int b = 0; b < NB; ++b) red[wave][b] = ss[b];
    }
    __syncthreads();
#pragma unroll
    for (int b = 0; b < NB; ++b)
      r_[b] = rsqrtf((red[0][b] + red[1][b] + red[2][b] + red[3][b]) *
                         (1.0f / IN_F) +
                     1e-6f);
  }

  // ---------------- Phase 2: streamed dequant GEMV ----------------
  float acc[RPW][NB];
#pragma unroll
  for (int rr = 0; rr < RPW; ++rr)
#pragma unroll
    for (int b = 0; b < NB; ++b) acc[rr][b] = 0.f;

  const int lcol = lane * 4;
  for (int k = 0; k < 16; ++k) {
    const int col = k * 256 + lcol;

    // Issue all 7 nontemporal W loads up front: 7 independent 16B/lane loads
    // in flight per wave -> HBM latency fully covered at 8 waves/CU.
    v4i q[RPW];
#pragma unroll
    for (int rr = 0; rr < RPW; ++rr)
      q[rr] = __builtin_nontemporal_load(
          reinterpret_cast<const v4i*>(W + (row0 + rr) * IN_F + col));

    const int g = col >> 7;  // quant group (4 lane-cols share one group)
    float2 sm[RPW];
#pragma unroll
    for (int rr = 0; rr < RPW; ++rr) sm[rr] = smv[(row0 + rr) * NG + g];

    // Normalized activations on the fly (L2-resident x, nw).
    const float4 wv = *reinterpret_cast<const float4*>(nw + col);
    float4 xv[NB];
#pragma unroll
    for (int b = 0; b < NB; ++b) {
      const float4 v = *reinterpret_cast<const float4*>(x + b * IN_F + col);
      const float rb = r_[b];
      xv[b].x = v.x * rb * wv.x;
      xv[b].y = v.y * rb * wv.y;
      xv[b].z = v.z * rb * wv.z;
      xv[b].w = v.w * rb * wv.w;
    }

#pragma unroll
    for (int rr = 0; rr < RPW; ++rr) {
      const float w0 = fmaf((float)q[rr].x, sm[rr].x, sm[rr].y);
      const float w1 = fmaf((float)q[rr].y, sm[rr].x, sm[rr].y);
      const float w2 = fmaf((float)q[rr].z, sm[rr].x, sm[rr].y);
      const float w3 = fmaf((float)q[rr].w, sm[rr].x, sm[rr].y);
#pragma unroll
      for (int b = 0; b < NB; ++b) {
        acc[rr][b] = fmaf(w0, xv[b].x, acc[rr][b]);
        acc[rr][b] = fmaf(w1, xv[b].y, acc[rr][b]);
        acc[rr][b] = fmaf(w2, xv[b].z, acc[rr][b]);
        acc[rr][b] = fmaf(w3, xv[b].w, acc[rr][b]);
      }
    }
  }

  // ---------------- Epilogue ----------------
#pragma unroll
  for (int rr = 0; rr < RPW; ++rr)
#pragma unroll
    for (int b = 0; b < NB; ++b)
      p[lane][wave * (RPW * NB) + rr * NB + b] = acc[rr][b];
  __syncthreads();

  if (t < RPB * NB) {  // 224 outputs per block
    float s0 = 0.f, s1 = 0.f, s2 = 0.f, s3 = 0.f;
#pragma unroll
    for (int l = 0; l < 64; l += 4) {
      s0 += p[l + 0][t];
      s1 += p[l + 1][t];
      s2 += p[l + 2][t];
      s3 += p[l + 3][t];
    }
    const int r = t >> 3;  // local row
    const int b = t & 7;   // batch
    const int o = blockIdx.x * RPB + r;
    out[b * OUT_F + o] = (s0 + s1) + (s2 + s3) + bias[o];
  }
}

extern "C" void kernel_launch(void* const* d_in, const int* in_sizes, int n_in,
                              void* d_out, int out_size, void* d_ws,
                              size_t ws_size, hipStream_t stream) {
  const float* x = (const float*)d_in[0];
  const int* W = (const int*)d_in[1];
  const float2* smv = (const float2*)d_in[2];
  const float* nw = (const float*)d_in[3];
  const float* bias = (const float*)d_in[4];
  float* out = (float*)d_out;

  fused_gemv_k<<<NBLK, 256, 0, stream>>>(x, W, smv, nw, bias, out);
}